// Round 2
// baseline (24757.259 us; speedup 1.0000x reference)
//
#include <hip/hip_runtime.h>
#include <math.h>

#define N_BATCH 128
#define L_SEQ   2048
#define HD      128      // hidden dim
#define G4      512      // 4*H gates

__device__ __forceinline__ float sigmoidf_fast(float x) {
    return 1.0f / (1.0f + __expf(-x));   // stable both tails
}
__device__ __forceinline__ float tanhf_fast(float x) {
    float a = fabsf(x);
    float t = 1.0f - 2.0f / (1.0f + __expf(2.0f * a));  // exp overflow -> t=1
    return copysignf(t, x);
}

// gx[tc][n][j] = bias[j] + sum_k Z[row][k] * Wih[j][k],  row = tc*128+n (chunk-local)
// mode 0: Z = concat(x,w) gathered from global x,w at absolute timestep t0+tc
// mode 1: Z = hchunk rows (contiguous chunk-local buffer [ct*128][128])
// tile: 64 rows x 512 cols per block, 256 threads, each thread 2 cols x 64 rows
__global__ __launch_bounds__(256, 2) void gx_gemm(
        const float* __restrict__ x, const float* __restrict__ w,
        const float* __restrict__ hchunk,
        const float* __restrict__ Wih,
        const float* __restrict__ b_ih, const float* __restrict__ b_hh,
        float* __restrict__ gx, int t0, int mode)
{
    __shared__ __align__(16) float zt[64 * HD];   // 32 KB
    const int tid = threadIdx.x;
    const int rbase = blockIdx.x * 64;            // chunk-local row

    if (mode == 1) {
        const float4* __restrict__ s4 = (const float4*)(hchunk + (size_t)rbase * HD);
        float4* d4 = (float4*)zt;
        #pragma unroll
        for (int i = 0; i < 8; ++i) d4[tid + 256 * i] = s4[tid + 256 * i];
    } else {
        #pragma unroll
        for (int i = 0; i < 8; ++i) {
            int flat = tid + 256 * i;      // float4 index within tile (2048 total)
            int r = flat >> 5;             // 32 float4 per row
            int q = flat & 31;
            int gr = t0 * N_BATCH + rbase + r;   // absolute row = t*128+n
            int t = gr >> 7;
            int n = gr & 127;
            const float* s = (q < 16)
                ? (x + ((size_t)n * L_SEQ + t) * 64 + 4 * q)
                : (w + ((size_t)n * L_SEQ + t) * 64 + 4 * (q - 16));
            ((float4*)zt)[flat] = *(const float4*)s;
        }
    }
    __syncthreads();

    const int j0 = tid, j1 = tid + 256;
    float acc0[64], acc1[64];
    #pragma unroll
    for (int r = 0; r < 64; ++r) { acc0[r] = 0.f; acc1[r] = 0.f; }

    const float4* __restrict__ W0 = (const float4*)(Wih + (size_t)j0 * HD);
    const float4* __restrict__ W1 = (const float4*)(Wih + (size_t)j1 * HD);
    const float4* Z4 = (const float4*)zt;

    for (int k4 = 0; k4 < 32; ++k4) {
        float4 w0 = W0[k4];
        float4 w1 = W1[k4];
        const float4* zp = Z4 + k4;
        #pragma unroll
        for (int r = 0; r < 64; ++r) {
            float4 z = zp[r * 32];
            acc0[r] += z.x * w0.x + z.y * w0.y + z.z * w0.z + z.w * w0.w;
            acc1[r] += z.x * w1.x + z.y * w1.y + z.z * w1.z + z.w * w1.w;
        }
    }

    float bias0 = b_ih[j0] + b_hh[j0];
    float bias1 = b_ih[j1] + b_hh[j1];
    #pragma unroll
    for (int r = 0; r < 64; ++r) {
        size_t row = (size_t)(rbase + r) * G4;
        gx[row + j0] = acc0[r] + bias0;
        gx[row + j1] = acc1[r] + bias1;
    }
}

// Persistent recurrence over one chunk: 1 block per sample, 512 threads,
// thread j owns gate row j with W_hh row j resident in 32 float4 VGPRs.
// h broadcast via LDS (same-address reads = conflict-free broadcast).
__global__ __launch_bounds__(512, 2) void lstm_rec(
        const float* __restrict__ gx,     // [ct][128][512] chunk-local
        const float* __restrict__ Whh,    // [512][128]
        float* __restrict__ hout,         // [ct][128][128] chunk-local (may be unused)
        float* __restrict__ hprev,        // [128][128] carried h state
        float* __restrict__ cst,          // [128][128] carried c state
        int first, int ct, int write_h)
{
    const int n = blockIdx.x;
    const int j = threadIdx.x;
    __shared__ __align__(16) float hbuf[HD];
    __shared__ float gbuf[G4];

    float4 wr[32];
    const float4* __restrict__ Wr4 = (const float4*)(Whh + (size_t)j * HD);
    #pragma unroll
    for (int k4 = 0; k4 < 32; ++k4) wr[k4] = Wr4[k4];

    float c = 0.f;
    if (j < HD) {
        if (first) {
            hbuf[j] = 0.f;
        } else {
            hbuf[j] = hprev[(size_t)n * HD + j];
            c = cst[(size_t)n * HD + j];
        }
    }
    __syncthreads();

    const float* __restrict__ gxp = gx + (size_t)n * G4 + j;
    float gnext = gxp[0];
    float hlast = 0.f;
    for (int tc = 0; tc < ct; ++tc) {
        float g = gnext;
        int tn = (tc + 1 < ct) ? (tc + 1) : tc;
        gnext = gxp[(size_t)tn * N_BATCH * G4];   // prefetch next step's gx

        const float4* h4 = (const float4*)hbuf;
        float s0 = 0.f, s1 = 0.f, s2 = 0.f, s3 = 0.f;  // 4 chains for FMA latency
        #pragma unroll
        for (int k4 = 0; k4 < 32; ++k4) {
            float4 h = h4[k4];
            s0 += wr[k4].x * h.x;
            s1 += wr[k4].y * h.y;
            s2 += wr[k4].z * h.z;
            s3 += wr[k4].w * h.w;
        }
        g += (s0 + s1) + (s2 + s3);
        gbuf[j] = g;
        __syncthreads();

        if (j < HD) {
            float gi = sigmoidf_fast(gbuf[j]);
            float gf = sigmoidf_fast(gbuf[j + 128]);
            float gg = tanhf_fast(gbuf[j + 256]);
            float go = sigmoidf_fast(gbuf[j + 384]);
            c = gf * c + gi * gg;
            float h = go * tanhf_fast(c);
            hbuf[j] = h;
            hlast = h;
            if (write_h)
                hout[((size_t)tc * N_BATCH + n) * HD + j] = h;
        }
        __syncthreads();
    }
    if (j < HD) {
        hprev[(size_t)n * HD + j] = hlast;
        cst[(size_t)n * HD + j] = c;
    }
}

__global__ void final_lin(const float* __restrict__ hlast,   // [128][128]
                          const float* __restrict__ Wlin,
                          const float* __restrict__ blin,
                          float* __restrict__ out)
{
    int n = threadIdx.x;  // 128
    const float4* h4 = (const float4*)(hlast + (size_t)n * HD);
    const float4* w4 = (const float4*)Wlin;
    float s = 0.f;
    #pragma unroll
    for (int k4 = 0; k4 < 32; ++k4) {
        float4 h = h4[k4];
        float4 ww = w4[k4];
        s += h.x * ww.x + h.y * ww.y + h.z * ww.z + h.w * ww.w;
    }
    out[n] = s + blin[0];
}

extern "C" void kernel_launch(void* const* d_in, const int* in_sizes, int n_in,
                              void* d_out, int out_size, void* d_ws, size_t ws_size,
                              hipStream_t stream)
{
    const float* x = (const float*)d_in[0];
    const float* w = (const float*)d_in[1];
    const float* Wih[3] = {(const float*)d_in[2], (const float*)d_in[6], (const float*)d_in[10]};
    const float* Whh[3] = {(const float*)d_in[3], (const float*)d_in[7], (const float*)d_in[11]};
    const float* bih[3] = {(const float*)d_in[4], (const float*)d_in[8], (const float*)d_in[12]};
    const float* bhh[3] = {(const float*)d_in[5], (const float*)d_in[9], (const float*)d_in[13]};
    const float* Wlin = (const float*)d_in[14];
    const float* blin = (const float*)d_in[15];
    float* out = (float*)d_out;

    // Pick the largest chunk length that fits ws_size.
    // floats needed: gx ct*128*512 + 2 chunk h bufs ct*128*128 + 6 carry bufs 128*128
    int ct = 8;
    const int cands[6] = {256, 128, 64, 32, 16, 8};
    for (int i = 0; i < 6; ++i) {
        size_t need = ((size_t)cands[i] * 98304 + 98304) * sizeof(float);
        if (need <= ws_size) { ct = cands[i]; break; }
    }
    int nchunk = L_SEQ / ct;

    float* gx    = (float*)d_ws;
    float* hA    = gx + (size_t)ct * N_BATCH * G4;
    float* hB    = hA + (size_t)ct * N_BATCH * HD;
    float* carry = hB + (size_t)ct * N_BATCH * HD;   // 6 * 16384 floats
    float* hprev0 = carry;
    float* hprev1 = carry + 16384;
    float* hprev2 = carry + 2 * 16384;
    float* cst0   = carry + 3 * 16384;
    float* cst1   = carry + 4 * 16384;
    float* cst2   = carry + 5 * 16384;

    for (int ch = 0; ch < nchunk; ++ch) {
        int t0 = ch * ct;
        int first = (ch == 0) ? 1 : 0;
        // layer 1 (input = concat(x,w))
        gx_gemm<<<dim3(ct * 2), dim3(256), 0, stream>>>(
            x, w, nullptr, Wih[0], bih[0], bhh[0], gx, t0, 0);
        lstm_rec<<<dim3(N_BATCH), dim3(512), 0, stream>>>(
            gx, Whh[0], hA, hprev0, cst0, first, ct, 1);
        // layer 2
        gx_gemm<<<dim3(ct * 2), dim3(256), 0, stream>>>(
            x, w, hA, Wih[1], bih[1], bhh[1], gx, 0, 1);
        lstm_rec<<<dim3(N_BATCH), dim3(512), 0, stream>>>(
            gx, Whh[1], hB, hprev1, cst1, first, ct, 1);
        // layer 3 (h sequence not needed downstream; only carry state)
        gx_gemm<<<dim3(ct * 2), dim3(256), 0, stream>>>(
            x, w, hB, Wih[2], bih[2], bhh[2], gx, 0, 1);
        lstm_rec<<<dim3(N_BATCH), dim3(512), 0, stream>>>(
            gx, Whh[2], hA, hprev2, cst2, first, ct, 0);
    }
    final_lin<<<dim3(1), dim3(128), 0, stream>>>(hprev2, Wlin, blin, out);
}

// Round 3
// 7801.726 us; speedup vs baseline: 3.1733x; 3.1733x over previous
//
#include <hip/hip_runtime.h>
#include <math.h>

#define N_BATCH 128
#define L_SEQ   2048
#define HD      128      // hidden dim
#define G4      512      // 4*H gates

__device__ __forceinline__ float sigmoidf_fast(float x) {
    return 1.0f / (1.0f + __expf(-x));   // stable both tails
}
__device__ __forceinline__ float tanhf_fast(float x) {
    float a = fabsf(x);
    float t = 1.0f - 2.0f / (1.0f + __expf(2.0f * a));  // exp overflow -> t=1
    return copysignf(t, x);
}

// Batched input-projection GEMM for up to 3 pipeline-active layers.
// grid (ct*4, 3): blockIdx.y = layer slot; tile 32 rows x 512 cols, 256 thr,
// thread = 2 cols (j, j+256) x 32 rows -> 64 accs (~92 VGPR, no spill).
// layer 0 gathers concat(x,w) at absolute chunk t0; layers 1,2 read h chunks.
__global__ __launch_bounds__(256) void gemm_batch(
        const float* __restrict__ x, const float* __restrict__ w,
        const float* __restrict__ z1, const float* __restrict__ z2,
        const float* __restrict__ Wih0, const float* __restrict__ Wih1,
        const float* __restrict__ Wih2,
        const float* __restrict__ bi0, const float* __restrict__ bi1,
        const float* __restrict__ bi2,
        const float* __restrict__ bh0, const float* __restrict__ bh1,
        const float* __restrict__ bh2,
        float* __restrict__ gx0, float* __restrict__ gx1, float* __restrict__ gx2,
        int t0, int a0, int a1, int a2)
{
    const int layer = blockIdx.y;
    if (layer == 0) { if (!a0) return; }
    else if (layer == 1) { if (!a1) return; }
    else { if (!a2) return; }

    const float* __restrict__ Wih = (layer == 0) ? Wih0 : (layer == 1) ? Wih1 : Wih2;
    const float* __restrict__ bi  = (layer == 0) ? bi0  : (layer == 1) ? bi1  : bi2;
    const float* __restrict__ bh  = (layer == 0) ? bh0  : (layer == 1) ? bh1  : bh2;
    float* __restrict__ gx        = (layer == 0) ? gx0  : (layer == 1) ? gx1  : gx2;

    __shared__ __align__(16) float zt[32 * HD];   // 16 KB
    const int tid = threadIdx.x;
    const int rbase = blockIdx.x * 32;            // chunk-local row

    if (layer == 0) {
        #pragma unroll
        for (int i = 0; i < 4; ++i) {
            int flat = tid + 256 * i;      // float4 index within tile (1024 total)
            int r = flat >> 5;             // 32 float4 per row
            int q = flat & 31;
            int gr = t0 * N_BATCH + rbase + r;   // absolute row = t*128+n
            int t = gr >> 7;
            int n = gr & 127;
            const float* s = (q < 16)
                ? (x + ((size_t)n * L_SEQ + t) * 64 + 4 * q)
                : (w + ((size_t)n * L_SEQ + t) * 64 + 4 * (q - 16));
            ((float4*)zt)[flat] = *(const float4*)s;
        }
    } else {
        const float* __restrict__ z = (layer == 1) ? z1 : z2;
        const float4* __restrict__ s4 = (const float4*)(z + (size_t)rbase * HD);
        float4* d4 = (float4*)zt;
        #pragma unroll
        for (int i = 0; i < 4; ++i) d4[tid + 256 * i] = s4[tid + 256 * i];
    }
    __syncthreads();

    const int j0 = tid, j1 = tid + 256;
    float acc0[32], acc1[32];
    #pragma unroll
    for (int r = 0; r < 32; ++r) { acc0[r] = 0.f; acc1[r] = 0.f; }

    const float4* __restrict__ W0 = (const float4*)(Wih + (size_t)j0 * HD);
    const float4* __restrict__ W1 = (const float4*)(Wih + (size_t)j1 * HD);
    const float4* Z4 = (const float4*)zt;

    for (int k4 = 0; k4 < 32; ++k4) {
        float4 w0 = W0[k4];
        float4 w1 = W1[k4];
        const float4* zp = Z4 + k4;
        #pragma unroll
        for (int r = 0; r < 32; ++r) {
            float4 z = zp[r * 32];        // same addr across wave: LDS broadcast
            acc0[r] += z.x * w0.x + z.y * w0.y + z.z * w0.z + z.w * w0.w;
            acc1[r] += z.x * w1.x + z.y * w1.y + z.z * w1.z + z.w * w1.w;
        }
    }

    float bias0 = bi[j0] + bh[j0];
    float bias1 = bi[j1] + bh[j1];
    #pragma unroll
    for (int r = 0; r < 32; ++r) {
        size_t row = (size_t)(rbase + r) * G4;
        gx[row + j0] = acc0[r] + bias0;
        gx[row + j1] = acc1[r] + bias1;
    }
}

// Batched recurrence over one chunk for up to 3 pipeline-active layers.
// grid (128, 3): blockIdx.x = sample, blockIdx.y = layer slot.
// 512 threads: thread j owns gate row j; W_hh row in 32 float4 VGPRs.
// waves_per_eu(2,2): VGPR budget 256 so the 128 weight regs never spill.
__global__ __launch_bounds__(512)
__attribute__((amdgpu_waves_per_eu(2, 2)))
void rec_batch(
        const float* __restrict__ gx0, const float* __restrict__ gx1,
        const float* __restrict__ gx2,
        const float* __restrict__ Wh0, const float* __restrict__ Wh1,
        const float* __restrict__ Wh2,
        float* __restrict__ o0, float* __restrict__ o1,
        float* __restrict__ carry,   // [6][128][128]: hprev0..2, cst0..2
        int a0, int a1, int a2, int f0, int f1, int f2, int ct)
{
    const int layer = blockIdx.y;
    if (layer == 0) { if (!a0) return; }
    else if (layer == 1) { if (!a1) return; }
    else { if (!a2) return; }

    const float* __restrict__ gx  = (layer == 0) ? gx0 : (layer == 1) ? gx1 : gx2;
    const float* __restrict__ Whh = (layer == 0) ? Wh0 : (layer == 1) ? Wh1 : Wh2;
    float* __restrict__ hout = (layer == 0) ? o0 : (layer == 1) ? o1 : nullptr;
    const int first   = (layer == 0) ? f0 : (layer == 1) ? f1 : f2;
    const int write_h = (layer < 2);
    float* __restrict__ hprev = carry + (size_t)layer * 16384;
    float* __restrict__ cst   = carry + (size_t)(3 + layer) * 16384;

    const int n = blockIdx.x;
    const int j = threadIdx.x;
    __shared__ __align__(16) float hbuf[HD];
    __shared__ float gbuf[G4];

    float4 wr[32];
    const float4* __restrict__ Wr4 = (const float4*)(Whh + (size_t)j * HD);
    #pragma unroll
    for (int k4 = 0; k4 < 32; ++k4) wr[k4] = Wr4[k4];

    float c = 0.f;
    if (j < HD) {
        if (first) {
            hbuf[j] = 0.f;
        } else {
            hbuf[j] = hprev[(size_t)n * HD + j];
            c = cst[(size_t)n * HD + j];
        }
    }
    __syncthreads();

    const float* __restrict__ gxp = gx + (size_t)n * G4 + j;
    float gnext = gxp[0];
    float hlast = 0.f;
    for (int tc = 0; tc < ct; ++tc) {
        float g = gnext;
        int tn = (tc + 1 < ct) ? (tc + 1) : tc;
        gnext = gxp[(size_t)tn * N_BATCH * G4];   // prefetch next step's gx

        const float4* h4 = (const float4*)hbuf;
        float s0 = 0.f, s1 = 0.f, s2 = 0.f, s3 = 0.f;  // 4 chains for FMA latency
        #pragma unroll
        for (int k4 = 0; k4 < 32; ++k4) {
            float4 h = h4[k4];
            s0 += wr[k4].x * h.x;
            s1 += wr[k4].y * h.y;
            s2 += wr[k4].z * h.z;
            s3 += wr[k4].w * h.w;
        }
        g += (s0 + s1) + (s2 + s3);
        gbuf[j] = g;
        __syncthreads();

        if (j < HD) {
            float gi = sigmoidf_fast(gbuf[j]);
            float gf = sigmoidf_fast(gbuf[j + 128]);
            float gg = tanhf_fast(gbuf[j + 256]);
            float go = sigmoidf_fast(gbuf[j + 384]);
            c = gf * c + gi * gg;
            float h = go * tanhf_fast(c);
            hbuf[j] = h;
            hlast = h;
            if (write_h)
                hout[((size_t)tc * N_BATCH + n) * HD + j] = h;
        }
        __syncthreads();
    }
    if (j < HD) {
        hprev[(size_t)n * HD + j] = hlast;
        cst[(size_t)n * HD + j] = c;
    }
}

__global__ void final_lin(const float* __restrict__ hlast,   // [128][128]
                          const float* __restrict__ Wlin,
                          const float* __restrict__ blin,
                          float* __restrict__ out)
{
    int n = threadIdx.x;  // 128
    const float4* h4 = (const float4*)(hlast + (size_t)n * HD);
    const float4* w4 = (const float4*)Wlin;
    float s = 0.f;
    #pragma unroll
    for (int k4 = 0; k4 < 32; ++k4) {
        float4 h = h4[k4];
        float4 ww = w4[k4];
        s += h.x * ww.x + h.y * ww.y + h.z * ww.z + h.w * ww.w;
    }
    out[n] = s + blin[0];
}

extern "C" void kernel_launch(void* const* d_in, const int* in_sizes, int n_in,
                              void* d_out, int out_size, void* d_ws, size_t ws_size,
                              hipStream_t stream)
{
    const float* x = (const float*)d_in[0];
    const float* w = (const float*)d_in[1];
    const float* Wih[3] = {(const float*)d_in[2], (const float*)d_in[6], (const float*)d_in[10]};
    const float* Whh[3] = {(const float*)d_in[3], (const float*)d_in[7], (const float*)d_in[11]};
    const float* bih[3] = {(const float*)d_in[4], (const float*)d_in[8], (const float*)d_in[12]};
    const float* bhh[3] = {(const float*)d_in[5], (const float*)d_in[9], (const float*)d_in[13]};
    const float* Wlin = (const float*)d_in[14];
    const float* blin = (const float*)d_in[15];
    float* out = (float*)d_out;

    // floats: 3 gx (ct*128*512) + 4 h chunk bufs (ct*128*128) + 6 carry (128*128)
    // = ct*262144 + 98304 floats
    int ct = 4;
    const int cands[6] = {128, 64, 32, 16, 8, 4};
    for (int i = 0; i < 6; ++i) {
        size_t need = ((size_t)cands[i] * 262144 + 98304) * sizeof(float);
        if (need <= ws_size) { ct = cands[i]; break; }
    }
    const int nchunk = L_SEQ / ct;

    float* gx[3];
    gx[0] = (float*)d_ws;
    gx[1] = gx[0] + (size_t)ct * N_BATCH * G4;
    gx[2] = gx[1] + (size_t)ct * N_BATCH * G4;
    float* h1[2]; float* h2[2];
    h1[0] = gx[2] + (size_t)ct * N_BATCH * G4;
    h1[1] = h1[0] + (size_t)ct * N_BATCH * HD;
    h2[0] = h1[1] + (size_t)ct * N_BATCH * HD;
    h2[1] = h2[0] + (size_t)ct * N_BATCH * HD;
    float* carry = h2[1] + (size_t)ct * N_BATCH * HD;  // 6 * 16384 floats

    // Pipeline: stage s runs (L0, chunk s), (L1, s-1), (L2, s-2)
    for (int s = 0; s < nchunk + 2; ++s) {
        int a0 = (s < nchunk);
        int a1 = (s >= 1 && s < nchunk + 1);
        int a2 = (s >= 2);
        const float* z1 = h1[(s - 1) & 1];
        const float* z2 = h2[s & 1];          // (s-2)&1 == s&1
        gemm_batch<<<dim3(ct * 4, 3), dim3(256), 0, stream>>>(
            x, w, z1, z2,
            Wih[0], Wih[1], Wih[2], bih[0], bih[1], bih[2],
            bhh[0], bhh[1], bhh[2], gx[0], gx[1], gx[2],
            s * ct, a0, a1, a2);
        rec_batch<<<dim3(N_BATCH, 3), dim3(512), 0, stream>>>(
            gx[0], gx[1], gx[2], Whh[0], Whh[1], Whh[2],
            h1[s & 1], h2[(s - 1) & 1], carry,
            a0, a1, a2, (s == 0), (s == 1), (s == 2), ct);
    }
    final_lin<<<dim3(1), dim3(128), 0, stream>>>(carry + 2 * 16384, Wlin, blin, out);
}

// Round 4
// 6253.113 us; speedup vs baseline: 3.9592x; 1.2477x over previous
//
#include <hip/hip_runtime.h>
#include <math.h>

#define N_BATCH 128
#define L_SEQ   2048
#define HD      128      // hidden dim
#define G4      512      // 4*H gates
#define LSTR    136      // LDS h row stride in bf16 (pad 8 -> worst 2-way bank alias)

typedef __bf16 bf16x8 __attribute__((ext_vector_type(8)));
typedef float  f32x4  __attribute__((ext_vector_type(4)));

__device__ __forceinline__ float sigmoidf_fast(float x) {
    return __builtin_amdgcn_rcpf(1.0f + __expf(-x));
}
__device__ __forceinline__ float tanhf_fast(float x) {
    float a = fabsf(x);
    float t = 1.0f - 2.0f * __builtin_amdgcn_rcpf(1.0f + __expf(2.0f * a));
    return copysignf(t, x);
}

// Split the 3 Whh matrices (512x128 fp32 each) into bf16 hi/lo pairs.
__global__ void split_w(const float* __restrict__ w0, const float* __restrict__ w1,
                        const float* __restrict__ w2,
                        __bf16* __restrict__ hi, __bf16* __restrict__ lo)
{
    int i = blockIdx.x * 256 + threadIdx.x;   // 0..196607
    int l = i >> 16;
    const float* src = (l == 0) ? w0 : (l == 1) ? w1 : w2;
    float v = src[i & 65535];
    __bf16 h = (__bf16)v;
    hi[i] = h;
    lo[i] = (__bf16)(v - (float)h);
}

// Batched input-projection GEMM for up to 3 pipeline-active layers.
// Writes gx in rec-friendly swizzled layout: gx[t][T][c][n], T=gate tile (0..31),
// c=col in tile (0..15), n=sample. Gate row j <-> (T=j>>4, c=j&15).
__global__ __launch_bounds__(256) void gemm_batch(
        const float* __restrict__ x, const float* __restrict__ w,
        const float* __restrict__ z1, const float* __restrict__ z2,
        const float* __restrict__ Wih0, const float* __restrict__ Wih1,
        const float* __restrict__ Wih2,
        const float* __restrict__ bi0, const float* __restrict__ bi1,
        const float* __restrict__ bi2,
        const float* __restrict__ bh0, const float* __restrict__ bh1,
        const float* __restrict__ bh2,
        float* __restrict__ gx0, float* __restrict__ gx1, float* __restrict__ gx2,
        int t0, int a0, int a1, int a2)
{
    const int layer = blockIdx.y;
    if (layer == 0) { if (!a0) return; }
    else if (layer == 1) { if (!a1) return; }
    else { if (!a2) return; }

    const float* __restrict__ Wih = (layer == 0) ? Wih0 : (layer == 1) ? Wih1 : Wih2;
    const float* __restrict__ bi  = (layer == 0) ? bi0  : (layer == 1) ? bi1  : bi2;
    const float* __restrict__ bh  = (layer == 0) ? bh0  : (layer == 1) ? bh1  : bh2;
    float* __restrict__ gx        = (layer == 0) ? gx0  : (layer == 1) ? gx1  : gx2;

    __shared__ __align__(16) float zt[32 * HD];   // 16 KB
    const int tid = threadIdx.x;
    const int rbase = blockIdx.x * 32;            // chunk-local row

    if (layer == 0) {
        #pragma unroll
        for (int i = 0; i < 4; ++i) {
            int flat = tid + 256 * i;      // float4 index within tile (1024 total)
            int r = flat >> 5;             // 32 float4 per row
            int qq = flat & 31;
            int gr = t0 * N_BATCH + rbase + r;   // absolute row = t*128+n
            int t = gr >> 7;
            int n = gr & 127;
            const float* s = (qq < 16)
                ? (x + ((size_t)n * L_SEQ + t) * 64 + 4 * qq)
                : (w + ((size_t)n * L_SEQ + t) * 64 + 4 * (qq - 16));
            ((float4*)zt)[flat] = *(const float4*)s;
        }
    } else {
        const float* __restrict__ z = (layer == 1) ? z1 : z2;
        const float4* __restrict__ s4 = (const float4*)(z + (size_t)rbase * HD);
        float4* d4 = (float4*)zt;
        #pragma unroll
        for (int i = 0; i < 4; ++i) d4[tid + 256 * i] = s4[tid + 256 * i];
    }
    __syncthreads();

    const int j0 = tid, j1 = tid + 256;
    float acc0[32], acc1[32];
    #pragma unroll
    for (int r = 0; r < 32; ++r) { acc0[r] = 0.f; acc1[r] = 0.f; }

    const float4* __restrict__ W0 = (const float4*)(Wih + (size_t)j0 * HD);
    const float4* __restrict__ W1 = (const float4*)(Wih + (size_t)j1 * HD);
    const float4* Z4 = (const float4*)zt;

    for (int k4 = 0; k4 < 32; ++k4) {
        float4 w0 = W0[k4];
        float4 w1 = W1[k4];
        const float4* zp = Z4 + k4;
        #pragma unroll
        for (int r = 0; r < 32; ++r) {
            float4 z = zp[r * 32];        // same addr across wave: LDS broadcast
            acc0[r] += z.x * w0.x + z.y * w0.y + z.z * w0.z + z.w * w0.w;
            acc1[r] += z.x * w1.x + z.y * w1.y + z.z * w1.z + z.w * w1.w;
        }
    }

    float bias0 = bi[j0] + bh[j0];
    float bias1 = bi[j1] + bh[j1];
    const int t = rbase >> 7;             // chunk-local timestep (32 | rbase)
    const int nbase = rbase & 127;
    float* p0 = gx + ((size_t)(t * 32 + (tid >> 4)) * 16 + (tid & 15)) * N_BATCH + nbase;
    float* p1 = gx + ((size_t)(t * 32 + (tid >> 4) + 16) * 16 + (tid & 15)) * N_BATCH + nbase;
    #pragma unroll
    for (int r = 0; r < 32; ++r) {
        p0[r] = acc0[r] + bias0;          // 32-float contiguous runs
        p1[r] = acc1[r] + bias1;
    }
}

// MFMA recurrence: grid (8, 3). Block owns 16 samples; 8 waves; wave w owns
// N-tiles {w,w+8,w+16,w+24} = gates i,f,g,o for hidden units 16w..16w+15.
// Whh hi/lo B-frags resident in VGPRs; h hi/lo via double-buffered LDS;
// c-state in VGPRs; 1 barrier/step; split-bf16 = 3 MFMAs per tile-kstep.
__global__ __launch_bounds__(512, 2) void rec_batch(
        const float* __restrict__ gx0, const float* __restrict__ gx1,
        const float* __restrict__ gx2,
        const __bf16* __restrict__ whh_hi, const __bf16* __restrict__ whh_lo,
        float* __restrict__ o0, float* __restrict__ o1,
        float* __restrict__ carry,   // [6][128][128]: hprev0..2, cst0..2
        int a0, int a1, int a2, int f0, int f1, int f2, int ct)
{
    const int layer = blockIdx.y;
    if (layer == 0) { if (!a0) return; }
    else if (layer == 1) { if (!a1) return; }
    else { if (!a2) return; }

    const float* __restrict__ gx = (layer == 0) ? gx0 : (layer == 1) ? gx1 : gx2;
    float* __restrict__ hout = (layer == 0) ? o0 : (layer == 1) ? o1 : nullptr;
    const int first = (layer == 0) ? f0 : (layer == 1) ? f1 : f2;
    const int write_h = (layer < 2);
    const __bf16* __restrict__ whi = whh_hi + (size_t)layer * 65536;
    const __bf16* __restrict__ wlo = whh_lo + (size_t)layer * 65536;
    float* __restrict__ hprev = carry + (size_t)layer * 16384;
    float* __restrict__ cst   = carry + (size_t)(3 + layer) * 16384;

    const int sbase = blockIdx.x * 16;
    const int tid = threadIdx.x;
    const int wv = tid >> 6, lane = tid & 63, q = lane >> 4, cc = lane & 15;

    __shared__ __align__(16) __bf16 hhi[2][16][LSTR];
    __shared__ __align__(16) __bf16 hlo[2][16][LSTR];

    // B fragments: lane holds Whh[ng][k], ng = 16*tile + cc, k = ks*32 + q*8 + j
    bf16x8 bh[4][4], bl[4][4];
    #pragma unroll
    for (int ti = 0; ti < 4; ++ti) {
        int ng = (wv + 8 * ti) * 16 + cc;
        #pragma unroll
        for (int ks = 0; ks < 4; ++ks) {
            bh[ti][ks] = *(const bf16x8*)(whi + (size_t)ng * HD + ks * 32 + q * 8);
            bl[ti][ks] = *(const bf16x8*)(wlo + (size_t)ng * HD + ks * 32 + q * 8);
        }
    }

    // init h LDS buffer 0 and c state
    if (first) {
        for (int i = tid; i < 2048; i += 512) {
            int s = i >> 7, u = i & 127;
            hhi[0][s][u] = (__bf16)0.0f; hlo[0][s][u] = (__bf16)0.0f;
        }
    } else {
        for (int i = tid; i < 2048; i += 512) {
            int s = i >> 7, u = i & 127;
            float v = hprev[(size_t)(sbase + s) * HD + u];
            __bf16 h = (__bf16)v;
            hhi[0][s][u] = h; hlo[0][s][u] = (__bf16)(v - (float)h);
        }
    }
    const int uu = wv * 16 + cc;          // this lane's hidden unit
    f32x4 cstate;
    if (first) {
        cstate[0] = 0.f; cstate[1] = 0.f; cstate[2] = 0.f; cstate[3] = 0.f;
    } else {
        #pragma unroll
        for (int r = 0; r < 4; ++r)
            cstate[r] = cst[(size_t)(sbase + 4 * q + r) * HD + uu];
    }
    __syncthreads();

    // gx pointers, layout [tc][T][c][n]: lane reads 4 samples (dwordx4) per tile
    const float* gxp[4];
    #pragma unroll
    for (int ti = 0; ti < 4; ++ti)
        gxp[ti] = gx + ((size_t)((wv + 8 * ti) * 16 + cc)) * N_BATCH + sbase + 4 * q;

    f32x4 gcur[4];
    #pragma unroll
    for (int ti = 0; ti < 4; ++ti) gcur[ti] = *(const f32x4*)(gxp[ti]);

    f32x4 hv;
    hv[0] = 0.f; hv[1] = 0.f; hv[2] = 0.f; hv[3] = 0.f;

    for (int tc = 0; tc < ct; ++tc) {
        const int rb = tc & 1, wb = rb ^ 1;
        const size_t off = (size_t)((tc + 1 < ct) ? tc + 1 : tc) * 65536;
        f32x4 gnx[4];
        #pragma unroll
        for (int ti = 0; ti < 4; ++ti) gnx[ti] = *(const f32x4*)(gxp[ti] + off);

        // A fragments: lane = sample cc, k = ks*32 + q*8 + j
        bf16x8 ahi[4], alo[4];
        #pragma unroll
        for (int ks = 0; ks < 4; ++ks) {
            ahi[ks] = *(const bf16x8*)&hhi[rb][cc][ks * 32 + q * 8];
            alo[ks] = *(const bf16x8*)&hlo[rb][cc][ks * 32 + q * 8];
        }

        f32x4 acc[4];
        #pragma unroll
        for (int ti = 0; ti < 4; ++ti) {
            f32x4 d = gcur[ti];
            #pragma unroll
            for (int ks = 0; ks < 4; ++ks)
                d = __builtin_amdgcn_mfma_f32_16x16x32_bf16(ahi[ks], bh[ti][ks], d, 0, 0, 0);
            #pragma unroll
            for (int ks = 0; ks < 4; ++ks)
                d = __builtin_amdgcn_mfma_f32_16x16x32_bf16(ahi[ks], bl[ti][ks], d, 0, 0, 0);
            #pragma unroll
            for (int ks = 0; ks < 4; ++ks)
                d = __builtin_amdgcn_mfma_f32_16x16x32_bf16(alo[ks], bh[ti][ks], d, 0, 0, 0);
            acc[ti] = d;
        }
        #pragma unroll
        for (int ti = 0; ti < 4; ++ti) gcur[ti] = gnx[ti];

        // activations: lane holds samples 4q..4q+3 (D rows), unit uu (D col)
        #pragma unroll
        for (int r = 0; r < 4; ++r) {
            float gi = sigmoidf_fast(acc[0][r]);
            float gf = sigmoidf_fast(acc[1][r]);
            float gg = tanhf_fast(acc[2][r]);
            float go = sigmoidf_fast(acc[3][r]);
            float cn = gf * cstate[r] + gi * gg;
            cstate[r] = cn;
            hv[r] = go * tanhf_fast(cn);
        }

        // write h (bf16 hi/lo) into the other LDS buffer
        #pragma unroll
        for (int r = 0; r < 4; ++r) {
            __bf16 hb = (__bf16)hv[r];
            hhi[wb][4 * q + r][uu] = hb;
            hlo[wb][4 * q + r][uu] = (__bf16)(hv[r] - (float)hb);
        }
        if (write_h) {
            #pragma unroll
            for (int r = 0; r < 4; ++r)
                hout[((size_t)tc * N_BATCH + sbase + 4 * q + r) * HD + uu] = hv[r];
        }
        __syncthreads();
    }

    #pragma unroll
    for (int r = 0; r < 4; ++r) {
        cst[(size_t)(sbase + 4 * q + r) * HD + uu] = cstate[r];
        hprev[(size_t)(sbase + 4 * q + r) * HD + uu] = hv[r];
    }
}

__global__ void final_lin(const float* __restrict__ hlast,   // [128][128]
                          const float* __restrict__ Wlin,
                          const float* __restrict__ blin,
                          float* __restrict__ out)
{
    int n = threadIdx.x;  // 128
    const float4* h4 = (const float4*)(hlast + (size_t)n * HD);
    const float4* w4 = (const float4*)Wlin;
    float s = 0.f;
    #pragma unroll
    for (int k4 = 0; k4 < 32; ++k4) {
        float4 h = h4[k4];
        float4 ww = w4[k4];
        s += h.x * ww.x + h.y * ww.y + h.z * ww.z + h.w * ww.w;
    }
    out[n] = s + blin[0];
}

extern "C" void kernel_launch(void* const* d_in, const int* in_sizes, int n_in,
                              void* d_out, int out_size, void* d_ws, size_t ws_size,
                              hipStream_t stream)
{
    const float* x = (const float*)d_in[0];
    const float* w = (const float*)d_in[1];
    const float* Wih[3] = {(const float*)d_in[2], (const float*)d_in[6], (const float*)d_in[10]};
    const float* Whh[3] = {(const float*)d_in[3], (const float*)d_in[7], (const float*)d_in[11]};
    const float* bih[3] = {(const float*)d_in[4], (const float*)d_in[8], (const float*)d_in[12]};
    const float* bhh[3] = {(const float*)d_in[5], (const float*)d_in[9], (const float*)d_in[13]};
    const float* Wlin = (const float*)d_in[14];
    const float* blin = (const float*)d_in[15];
    float* out = (float*)d_out;

    // floats: 3 gx (ct*65536) + 4 h chunk bufs (ct*16384) + carry 98304
    //         + whh hi/lo 2*3*65536 bf16 = 196608 floats
    int ct = 4;
    const int cands[6] = {128, 64, 32, 16, 8, 4};
    for (int i = 0; i < 6; ++i) {
        size_t need = ((size_t)cands[i] * 262144 + 98304 + 196608) * sizeof(float);
        if (need <= ws_size) { ct = cands[i]; break; }
    }
    const int nchunk = L_SEQ / ct;

    float* gxb[3];
    gxb[0] = (float*)d_ws;
    gxb[1] = gxb[0] + (size_t)ct * N_BATCH * G4;
    gxb[2] = gxb[1] + (size_t)ct * N_BATCH * G4;
    float* h1[2]; float* h2[2];
    h1[0] = gxb[2] + (size_t)ct * N_BATCH * G4;
    h1[1] = h1[0] + (size_t)ct * N_BATCH * HD;
    h2[0] = h1[1] + (size_t)ct * N_BATCH * HD;
    h2[1] = h2[0] + (size_t)ct * N_BATCH * HD;
    float* carry = h2[1] + (size_t)ct * N_BATCH * HD;  // 6 * 16384 floats
    __bf16* whh_hi = (__bf16*)(carry + 6 * 16384);
    __bf16* whh_lo = whh_hi + 3 * 65536;

    split_w<<<dim3(768), dim3(256), 0, stream>>>(Whh[0], Whh[1], Whh[2], whh_hi, whh_lo);

    // Pipeline: stage s runs (L0, chunk s), (L1, s-1), (L2, s-2)
    for (int s = 0; s < nchunk + 2; ++s) {
        int a0 = (s < nchunk);
        int a1 = (s >= 1 && s < nchunk + 1);
        int a2 = (s >= 2);
        const float* z1 = h1[(s - 1) & 1];
        const float* z2 = h2[s & 1];          // (s-2)&1 == s&1
        gemm_batch<<<dim3(ct * 4, 3), dim3(256), 0, stream>>>(
            x, w, z1, z2,
            Wih[0], Wih[1], Wih[2], bih[0], bih[1], bih[2],
            bhh[0], bhh[1], bhh[2], gxb[0], gxb[1], gxb[2],
            s * ct, a0, a1, a2);
        rec_batch<<<dim3(8, 3), dim3(512), 0, stream>>>(
            gxb[0], gxb[1], gxb[2], whh_hi, whh_lo,
            h1[s & 1], h2[(s - 1) & 1], carry,
            a0, a1, a2, (s == 0), (s == 1), (s == 2), ct);
    }
    final_lin<<<dim3(1), dim3(128), 0, stream>>>(carry + 2 * 16384, Wlin, blin, out);
}

// Round 5
// 5928.890 us; speedup vs baseline: 4.1757x; 1.0547x over previous
//
#include <hip/hip_runtime.h>
#include <math.h>

#define N_BATCH 128
#define L_SEQ   2048
#define HD      128
#define G4      512
#define LSTR    136   // LDS h row stride (bf16), pad 8

typedef __bf16 bf16x8 __attribute__((ext_vector_type(8)));
typedef float  f32x4  __attribute__((ext_vector_type(4)));

__device__ __forceinline__ float sigmoidf_fast(float x) {
    return __builtin_amdgcn_rcpf(1.0f + __expf(-x));
}
__device__ __forceinline__ float tanhf_fast(float x) {
    float a = fabsf(x);
    float t = 1.0f - 2.0f * __builtin_amdgcn_rcpf(1.0f + __expf(2.0f * a));
    return copysignf(t, x);
}
__device__ __forceinline__ void split8(const float* p, bf16x8& h, bf16x8& l) {
    #pragma unroll
    for (int e = 0; e < 8; ++e) {
        float v = p[e];
        __bf16 hb = (__bf16)v;
        h[e] = hb;
        l[e] = (__bf16)(v - (float)hb);
    }
}

// Prep: split Whh and Wih (each [3][512][128] fp32) into bf16 hi/lo; bsum = bih+bhh.
__global__ void prep_split(const float* __restrict__ wh0, const float* __restrict__ wh1,
                           const float* __restrict__ wh2,
                           const float* __restrict__ wi0, const float* __restrict__ wi1,
                           const float* __restrict__ wi2,
                           const float* __restrict__ bi0, const float* __restrict__ bi1,
                           const float* __restrict__ bi2,
                           const float* __restrict__ bh0, const float* __restrict__ bh1,
                           const float* __restrict__ bh2,
                           __bf16* __restrict__ whh_hi, __bf16* __restrict__ whh_lo,
                           __bf16* __restrict__ wih_hi, __bf16* __restrict__ wih_lo,
                           float* __restrict__ bsum)
{
    int i = blockIdx.x * 256 + threadIdx.x;    // 0..393215
    if (i < 196608) {
        int l = i >> 16;
        const float* src = (l == 0) ? wh0 : (l == 1) ? wh1 : wh2;
        float v = src[i & 65535];
        __bf16 h = (__bf16)v;
        whh_hi[i] = h; whh_lo[i] = (__bf16)(v - (float)h);
    } else {
        int j = i - 196608;
        int l = j >> 16;
        const float* src = (l == 0) ? wi0 : (l == 1) ? wi1 : wi2;
        float v = src[j & 65535];
        __bf16 h = (__bf16)v;
        wih_hi[j] = h; wih_lo[j] = (__bf16)(v - (float)h);
    }
    if (i < 1536) {
        int l = i >> 9, k = i & 511;
        const float* bi = (l == 0) ? bi0 : (l == 1) ? bi1 : bi2;
        const float* bh = (l == 0) ? bh0 : (l == 1) ? bh1 : bh2;
        bsum[i] = bi[k] + bh[k];
    }
}

// Merged stage kernel. blockIdx.x < 96: recurrence (layer = bx/32, 4 samples each,
// consuming chunk d-2*layer). Else: MFMA input-projection gemm producing chunk
// (d+1-2*layer)'s gx for next dispatch. Roles are independent within a dispatch.
__global__ __launch_bounds__(512, 2) void stage_kernel(
        const float* __restrict__ x, const float* __restrict__ w,
        const __bf16* __restrict__ whh_hi, const __bf16* __restrict__ whh_lo,
        const __bf16* __restrict__ wih_hi, const __bf16* __restrict__ wih_lo,
        const float* __restrict__ bsum,
        float* __restrict__ gxbase,          // [par][layer][ct][512][128]
        __bf16* __restrict__ z1hi, __bf16* __restrict__ z1lo,  // [par][ct][128][128]
        __bf16* __restrict__ z2hi, __bf16* __restrict__ z2lo,
        float* __restrict__ carry,           // [6][128][128]
        int d, int ct, int nchunk)
{
    const int bx = blockIdx.x;
    const int tid = threadIdx.x;
    const int wv = tid >> 6, lane = tid & 63, q = lane >> 4, cc = lane & 15;
    const size_t gxchunk = (size_t)ct * 65536;
    const size_t zchunk = (size_t)ct * 16384;

    if (bx < 96) {
        // ---------------- recurrence role ----------------
        const int lr = bx >> 5;
        const int cr = d - 2 * lr;
        if (cr < 0 || cr >= nchunk) return;
        const int sbase = (bx & 31) * 4;
        const int first = (cr == 0);
        const float* __restrict__ gx = gxbase + ((size_t)((d & 1) * 3 + lr)) * gxchunk;
        __bf16* zho = (lr == 0) ? z1hi + (d & 1) * zchunk
                     : (lr == 1) ? z2hi + (d & 1) * zchunk : nullptr;
        __bf16* zlo_ = (lr == 0) ? z1lo + (d & 1) * zchunk
                      : (lr == 1) ? z2lo + (d & 1) * zchunk : nullptr;
        const __bf16* __restrict__ whi = whh_hi + (size_t)lr * 65536;
        const __bf16* __restrict__ wlo = whh_lo + (size_t)lr * 65536;
        float* __restrict__ hprev = carry + (size_t)lr * 16384;
        float* __restrict__ cst   = carry + (size_t)(3 + lr) * 16384;

        __shared__ __align__(16) __bf16 hhi[2][16][LSTR];
        __shared__ __align__(16) __bf16 hlo[2][16][LSTR];

        // B frags: Whh rows ng = (wv+8*ti)*16+cc (verified R4 layout)
        bf16x8 bh[4][4], bl[4][4];
        #pragma unroll
        for (int ti = 0; ti < 4; ++ti) {
            int ng = (wv + 8 * ti) * 16 + cc;
            #pragma unroll
            for (int ks = 0; ks < 4; ++ks) {
                bh[ti][ks] = *(const bf16x8*)(whi + (size_t)ng * HD + ks * 32 + q * 8);
                bl[ti][ks] = *(const bf16x8*)(wlo + (size_t)ng * HD + ks * 32 + q * 8);
            }
        }

        // init LDS h (rows 0..3 real, 4..15 zero, both buffers) and c state
        for (int i = tid; i < 4096; i += 512) {
            int b = i >> 11, s = (i >> 7) & 15, u = i & 127;
            float v = 0.f;
            if (b == 0 && s < 4 && !first) v = hprev[(size_t)(sbase + s) * HD + u];
            __bf16 hb = (__bf16)v;
            hhi[b][s][u] = hb; hlo[b][s][u] = (__bf16)(v - (float)hb);
        }
        const int uu = wv * 16 + cc;
        f32x4 cstate; cstate[0] = cstate[1] = cstate[2] = cstate[3] = 0.f;
        if (q == 0 && !first) {
            #pragma unroll
            for (int r = 0; r < 4; ++r)
                cstate[r] = cst[(size_t)(sbase + r) * HD + uu];
        }
        __syncthreads();

        // gx pointers: [tc][gate][n], f32x4 over samples sbase..sbase+3 (q==0 only)
        const float* gp[4];
        #pragma unroll
        for (int ti = 0; ti < 4; ++ti)
            gp[ti] = gx + (size_t)((wv + 8 * ti) * 16 + cc) * N_BATCH + sbase;

        f32x4 zero4; zero4[0] = zero4[1] = zero4[2] = zero4[3] = 0.f;
        f32x4 gcur[4];
        #pragma unroll
        for (int ti = 0; ti < 4; ++ti)
            gcur[ti] = (q == 0) ? *(const f32x4*)(gp[ti]) : zero4;

        float hv[4] = {0.f, 0.f, 0.f, 0.f};

        for (int tc = 0; tc < ct; ++tc) {
            const int rb = tc & 1, wb = rb ^ 1;
            const size_t off = (size_t)((tc + 1 < ct) ? tc + 1 : tc) * 65536;
            f32x4 gnx[4];
            #pragma unroll
            for (int ti = 0; ti < 4; ++ti)
                gnx[ti] = (q == 0) ? *(const f32x4*)(gp[ti] + off) : zero4;

            bf16x8 ahi[4], alo[4];
            #pragma unroll
            for (int ks = 0; ks < 4; ++ks) {
                ahi[ks] = *(const bf16x8*)&hhi[rb][cc][ks * 32 + q * 8];
                alo[ks] = *(const bf16x8*)&hlo[rb][cc][ks * 32 + q * 8];
            }

            f32x4 acc[4];
            #pragma unroll
            for (int ti = 0; ti < 4; ++ti) {
                f32x4 dd = gcur[ti];
                #pragma unroll
                for (int ks = 0; ks < 4; ++ks)
                    dd = __builtin_amdgcn_mfma_f32_16x16x32_bf16(ahi[ks], bh[ti][ks], dd, 0, 0, 0);
                #pragma unroll
                for (int ks = 0; ks < 4; ++ks)
                    dd = __builtin_amdgcn_mfma_f32_16x16x32_bf16(ahi[ks], bl[ti][ks], dd, 0, 0, 0);
                #pragma unroll
                for (int ks = 0; ks < 4; ++ks)
                    dd = __builtin_amdgcn_mfma_f32_16x16x32_bf16(alo[ks], bh[ti][ks], dd, 0, 0, 0);
                acc[ti] = dd;
            }
            #pragma unroll
            for (int ti = 0; ti < 4; ++ti) gcur[ti] = gnx[ti];

            if (q == 0) {
                #pragma unroll
                for (int r = 0; r < 4; ++r) {
                    float gi = sigmoidf_fast(acc[0][r]);
                    float gf = sigmoidf_fast(acc[1][r]);
                    float gg = tanhf_fast(acc[2][r]);
                    float go = sigmoidf_fast(acc[3][r]);
                    float cn = gf * cstate[r] + gi * gg;
                    cstate[r] = cn;
                    hv[r] = go * tanhf_fast(cn);
                    __bf16 hb = (__bf16)hv[r];
                    __bf16 lb = (__bf16)(hv[r] - (float)hb);
                    hhi[wb][r][uu] = hb;
                    hlo[wb][r][uu] = lb;
                    if (zho) {
                        size_t zi = ((size_t)tc * N_BATCH + sbase + r) * HD + uu;
                        zho[zi] = hb; zlo_[zi] = lb;
                    }
                }
            }
            __syncthreads();
        }
        if (q == 0) {
            #pragma unroll
            for (int r = 0; r < 4; ++r) {
                cst[(size_t)(sbase + r) * HD + uu] = cstate[r];
                hprev[(size_t)(sbase + r) * HD + uu] = hv[r];
            }
        }
    } else {
        // ---------------- gemm role (produces gx for dispatch d+1) ----------------
        const int g = bx - 96;
        const int perl = 8 * ct;                 // 4 gate-blocks x 2ct col-blocks
        const int lg = g / perl;
        const int r0 = g - lg * perl;
        const int gb = r0 / (2 * ct);
        const int cb = r0 - gb * (2 * ct);
        const int cg = d + 1 - 2 * lg;
        if (cg < 0 || cg >= nchunk) return;
        const int tc = cb >> 1, n0 = (cb & 1) * 64;

        float* __restrict__ gxo = gxbase + ((size_t)(((d + 1) & 1) * 3 + lg)) * gxchunk
                                  + (size_t)tc * 65536;
        const __bf16* zh = nullptr; const __bf16* zl = nullptr;
        if (lg > 0) {
            size_t po = (size_t)((d & 1) ^ 1) * zchunk;
            zh = ((lg == 1) ? z1hi : z2hi) + po;
            zl = ((lg == 1) ? z1lo : z2lo) + po;
        }

        const int mt0 = gb * 8 + (wv & 3) * 2;   // M-tiles (gates mt*16)
        const int nt0 = (wv >> 2) * 2;           // N-tiles of this block's 4

        // A frags: Wih hi/lo rows (mt)*16+cc
        bf16x8 ah[2][4], al[2][4];
        #pragma unroll
        for (int mm = 0; mm < 2; ++mm) {
            int row = (mt0 + mm) * 16 + cc;
            #pragma unroll
            for (int ks = 0; ks < 4; ++ks) {
                ah[mm][ks] = *(const bf16x8*)(wih_hi + (size_t)lg * 65536 + (size_t)row * HD + ks * 32 + q * 8);
                al[mm][ks] = *(const bf16x8*)(wih_lo + (size_t)lg * 65536 + (size_t)row * HD + ks * 32 + q * 8);
            }
        }
        // B frags: z hi/lo, col n = n0 + nt*16 + cc
        bf16x8 zbh[2][4], zbl[2][4];
        #pragma unroll
        for (int nn = 0; nn < 2; ++nn) {
            int n = n0 + (nt0 + nn) * 16 + cc;
            if (lg == 0) {
                int tg = cg * ct + tc;
                #pragma unroll
                for (int ks = 0; ks < 4; ++ks) {
                    const float* src = (ks < 2 ? x : w)
                        + ((size_t)n * L_SEQ + tg) * 64 + (ks & 1) * 32 + q * 8;
                    split8(src, zbh[nn][ks], zbl[nn][ks]);
                }
            } else {
                size_t row = (size_t)tc * N_BATCH + n;
                #pragma unroll
                for (int ks = 0; ks < 4; ++ks) {
                    zbh[nn][ks] = *(const bf16x8*)(zh + row * HD + ks * 32 + q * 8);
                    zbl[nn][ks] = *(const bf16x8*)(zl + row * HD + ks * 32 + q * 8);
                }
            }
        }

        f32x4 acc[2][2];
        #pragma unroll
        for (int mm = 0; mm < 2; ++mm)
            #pragma unroll
            for (int nn = 0; nn < 2; ++nn)
                acc[mm][nn][0] = acc[mm][nn][1] = acc[mm][nn][2] = acc[mm][nn][3] = 0.f;

        #pragma unroll
        for (int mm = 0; mm < 2; ++mm)
            #pragma unroll
            for (int nn = 0; nn < 2; ++nn) {
                f32x4 dd = acc[mm][nn];
                #pragma unroll
                for (int ks = 0; ks < 4; ++ks)
                    dd = __builtin_amdgcn_mfma_f32_16x16x32_bf16(ah[mm][ks], zbh[nn][ks], dd, 0, 0, 0);
                #pragma unroll
                for (int ks = 0; ks < 4; ++ks)
                    dd = __builtin_amdgcn_mfma_f32_16x16x32_bf16(ah[mm][ks], zbl[nn][ks], dd, 0, 0, 0);
                #pragma unroll
                for (int ks = 0; ks < 4; ++ks)
                    dd = __builtin_amdgcn_mfma_f32_16x16x32_bf16(al[mm][ks], zbh[nn][ks], dd, 0, 0, 0);
                acc[mm][nn] = dd;
            }

        #pragma unroll
        for (int mm = 0; mm < 2; ++mm) {
            f32x4 bb = *(const f32x4*)(bsum + (size_t)lg * G4 + (mt0 + mm) * 16 + 4 * q);
            #pragma unroll
            for (int nn = 0; nn < 2; ++nn) {
                int n = n0 + (nt0 + nn) * 16 + cc;
                #pragma unroll
                for (int rr = 0; rr < 4; ++rr) {
                    int grow = (mt0 + mm) * 16 + 4 * q + rr;
                    gxo[(size_t)grow * N_BATCH + n] = acc[mm][nn][rr] + bb[rr];
                }
            }
        }
    }
}

__global__ void final_lin(const float* __restrict__ hlast,
                          const float* __restrict__ Wlin,
                          const float* __restrict__ blin,
                          float* __restrict__ out)
{
    int n = threadIdx.x;  // 128
    const float4* h4 = (const float4*)(hlast + (size_t)n * HD);
    const float4* w4 = (const float4*)Wlin;
    float s = 0.f;
    #pragma unroll
    for (int k4 = 0; k4 < 32; ++k4) {
        float4 h = h4[k4];
        float4 ww = w4[k4];
        s += h.x * ww.x + h.y * ww.y + h.z * ww.z + h.w * ww.w;
    }
    out[n] = s + blin[0];
}

extern "C" void kernel_launch(void* const* d_in, const int* in_sizes, int n_in,
                              void* d_out, int out_size, void* d_ws, size_t ws_size,
                              hipStream_t stream)
{
    const float* x = (const float*)d_in[0];
    const float* w = (const float*)d_in[1];
    const float* Wih[3] = {(const float*)d_in[2], (const float*)d_in[6], (const float*)d_in[10]};
    const float* Whh[3] = {(const float*)d_in[3], (const float*)d_in[7], (const float*)d_in[11]};
    const float* bih[3] = {(const float*)d_in[4], (const float*)d_in[8], (const float*)d_in[12]};
    const float* bhh[3] = {(const float*)d_in[5], (const float*)d_in[9], (const float*)d_in[13]};
    const float* Wlin = (const float*)d_in[14];
    const float* blin = (const float*)d_in[15];
    float* out = (float*)d_out;

    // bytes = 1,835,008*ct + ~2MB fixed
    int ct = 8;
    const int cands[4] = {64, 32, 16, 8};
    for (int i = 0; i < 4; ++i) {
        size_t need = 1835008ull * cands[i] + 2100000ull;
        if (need <= ws_size) { ct = cands[i]; break; }
    }
    const int nchunk = L_SEQ / ct;

    float* gxbase = (float*)d_ws;                       // 6*ct*65536 floats
    float* carry  = gxbase + (size_t)6 * ct * 65536;    // 98304 floats
    float* bsum   = carry + 98304;                      // 1536 floats
    __bf16* whh_hi = (__bf16*)(bsum + 1536);
    __bf16* whh_lo = whh_hi + 196608;
    __bf16* wih_hi = whh_lo + 196608;
    __bf16* wih_lo = wih_hi + 196608;
    __bf16* z1hi = wih_lo + 196608;                     // each 2*ct*16384 bf16
    __bf16* z1lo = z1hi + (size_t)2 * ct * 16384;
    __bf16* z2hi = z1lo + (size_t)2 * ct * 16384;
    __bf16* z2lo = z2hi + (size_t)2 * ct * 16384;

    prep_split<<<dim3(1536), dim3(256), 0, stream>>>(
        Whh[0], Whh[1], Whh[2], Wih[0], Wih[1], Wih[2],
        bih[0], bih[1], bih[2], bhh[0], bhh[1], bhh[2],
        whh_hi, whh_lo, wih_hi, wih_lo, bsum);

    const int nblk = 96 + 24 * ct;
    for (int d = -1; d <= nchunk + 3; ++d) {
        stage_kernel<<<dim3(nblk), dim3(512), 0, stream>>>(
            x, w, whh_hi, whh_lo, wih_hi, wih_lo, bsum,
            gxbase, z1hi, z1lo, z2hi, z2lo, carry, d, ct, nchunk);
    }
    final_lin<<<dim3(1), dim3(128), 0, stream>>>(carry + 2 * 16384, Wlin, blin, out);
}

// Round 6
// 3684.277 us; speedup vs baseline: 6.7197x; 1.6092x over previous
//
#include <hip/hip_runtime.h>
#include <math.h>

#define N_BATCH 128
#define L_SEQ   2048
#define HD      128
#define G4      512

typedef __bf16 bf16x8 __attribute__((ext_vector_type(8)));
typedef float  f32x4  __attribute__((ext_vector_type(4)));

__device__ __forceinline__ float sigmoidf_fast(float x) {
    return __builtin_amdgcn_rcpf(1.0f + __expf(-x));
}
__device__ __forceinline__ float tanhf_fast(float x) {
    float a = fabsf(x);
    float t = 1.0f - 2.0f * __builtin_amdgcn_rcpf(1.0f + __expf(2.0f * a));
    return copysignf(t, x);
}
__device__ __forceinline__ void split8(const float* p, bf16x8& h, bf16x8& l) {
    #pragma unroll
    for (int e = 0; e < 8; ++e) {
        float v = p[e];
        __bf16 hb = (__bf16)v;
        h[e] = hb;
        l[e] = (__bf16)(v - (float)hb);
    }
}

// Split Whh and Wih ([3][512][128] fp32) into bf16 hi/lo; bsum = bih+bhh.
__global__ void prep_split(const float* __restrict__ wh0, const float* __restrict__ wh1,
                           const float* __restrict__ wh2,
                           const float* __restrict__ wi0, const float* __restrict__ wi1,
                           const float* __restrict__ wi2,
                           const float* __restrict__ bi0, const float* __restrict__ bi1,
                           const float* __restrict__ bi2,
                           const float* __restrict__ bh0, const float* __restrict__ bh1,
                           const float* __restrict__ bh2,
                           __bf16* __restrict__ whh_hi, __bf16* __restrict__ whh_lo,
                           __bf16* __restrict__ wih_hi, __bf16* __restrict__ wih_lo,
                           float* __restrict__ bsum)
{
    int i = blockIdx.x * 256 + threadIdx.x;    // 0..393215
    if (i < 196608) {
        int l = i >> 16;
        const float* src = (l == 0) ? wh0 : (l == 1) ? wh1 : wh2;
        float v = src[i & 65535];
        __bf16 h = (__bf16)v;
        whh_hi[i] = h; whh_lo[i] = (__bf16)(v - (float)h);
    } else {
        int j = i - 196608;
        int l = j >> 16;
        const float* src = (l == 0) ? wi0 : (l == 1) ? wi1 : wi2;
        float v = src[j & 65535];
        __bf16 h = (__bf16)v;
        wih_hi[j] = h; wih_lo[j] = (__bf16)(v - (float)h);
    }
    if (i < 1536) {
        int l = i >> 9, k = i & 511;
        const float* bi = (l == 0) ? bi0 : (l == 1) ? bi1 : bi2;
        const float* bh = (l == 0) ? bh0 : (l == 1) ? bh1 : bh2;
        bsum[i] = bi[k] + bh[k];
    }
}

// gx layout: [parity*3+layer][t][sblk(8)][gate(512)][sample(16)] floats.
// z layout:  [parity][t*128 + sample][unit] bf16 (hi and lo planes).
// Stage kernel: bx<24 = recurrence (8 blocks/layer x 16 samples, chunk d-2*lr);
// else MFMA gemm producing chunk (d+1-2*lg)'s gx.
__global__ __launch_bounds__(512, 2) void stage_kernel(
        const float* __restrict__ x, const float* __restrict__ w,
        const __bf16* __restrict__ whh_hi, const __bf16* __restrict__ whh_lo,
        const __bf16* __restrict__ wih_hi, const __bf16* __restrict__ wih_lo,
        const float* __restrict__ bsum,
        float* __restrict__ gxbase,
        __bf16* __restrict__ z1hi, __bf16* __restrict__ z1lo,
        __bf16* __restrict__ z2hi, __bf16* __restrict__ z2lo,
        float* __restrict__ carry,           // [6][128][128]
        int d, int ct, int nchunk)
{
    const int bx = blockIdx.x;
    const int tid = threadIdx.x;
    const int wv = tid >> 6, lane = tid & 63, q = lane >> 4, cc = lane & 15;
    const size_t gxl = (size_t)ct * 65536;
    const size_t zchunk = (size_t)ct * 16384;

    // h in MFMA-A-fragment order: [buf][g=unit>>3][sample][unit&7]
    __shared__ __align__(16) __bf16 hfhi[2][16][16][8];   // 8 KB
    __shared__ __align__(16) __bf16 hflo[2][16][16][8];   // 8 KB

    if (bx < 24) {
        // ---------------- recurrence role ----------------
        const int lr = bx >> 3;
        const int cr = d - 2 * lr;
        if (cr < 0 || cr >= nchunk) return;
        const int sblk = bx & 7, sbase = sblk * 16;
        const int first = (cr == 0);
        const float* __restrict__ gx =
            gxbase + (size_t)((d & 1) * 3 + lr) * gxl + (size_t)sblk * 8192;
        __bf16* zho = (lr == 0) ? z1hi + (d & 1) * zchunk
                     : (lr == 1) ? z2hi + (d & 1) * zchunk : nullptr;
        __bf16* zlo_ = (lr == 0) ? z1lo + (d & 1) * zchunk
                      : (lr == 1) ? z2lo + (d & 1) * zchunk : nullptr;
        const __bf16* __restrict__ whi = whh_hi + (size_t)lr * 65536;
        const __bf16* __restrict__ wlo = whh_lo + (size_t)lr * 65536;
        float* __restrict__ hprev = carry + (size_t)lr * 16384;
        float* __restrict__ cst   = carry + (size_t)(3 + lr) * 16384;

        // B frags: Whh rows ng=(wv+8*ti)*16+cc, k=ks*32+q*8+j  (R4-verified)
        bf16x8 bh[4][4], bl[4][4];
        #pragma unroll
        for (int ti = 0; ti < 4; ++ti) {
            int ng = (wv + 8 * ti) * 16 + cc;
            #pragma unroll
            for (int ks = 0; ks < 4; ++ks) {
                bh[ti][ks] = *(const bf16x8*)(whi + (size_t)ng * HD + ks * 32 + q * 8);
                bl[ti][ks] = *(const bf16x8*)(wlo + (size_t)ng * HD + ks * 32 + q * 8);
            }
        }

        // init h fragment buffer 0 and c state
        for (int i = tid; i < 2048; i += 512) {
            int m = i >> 7, u = i & 127;
            float v = first ? 0.f : hprev[(size_t)(sbase + m) * HD + u];
            __bf16 hb = (__bf16)v;
            hfhi[0][u >> 3][m][u & 7] = hb;
            hflo[0][u >> 3][m][u & 7] = (__bf16)(v - (float)hb);
        }
        const int uu = wv * 16 + cc;
        f32x4 cstate; cstate[0] = cstate[1] = cstate[2] = cstate[3] = 0.f;
        if (!first) {
            #pragma unroll
            for (int r = 0; r < 4; ++r)
                cstate[r] = cst[(size_t)(sbase + 4 * q + r) * HD + uu];
        }
        __syncthreads();

        // gx: lane reads f32x4 at gate*16 + 4q (contiguous 1 KB per wave-tile)
        f32x4 gcur[4];
        #pragma unroll
        for (int ti = 0; ti < 4; ++ti)
            gcur[ti] = *(const f32x4*)(gx + (size_t)((wv + 8 * ti) * 16 + cc) * 16 + 4 * q);

        float hv[4] = {0.f, 0.f, 0.f, 0.f};

        for (int tc = 0; tc < ct; ++tc) {
            const int rb = tc & 1, wb = rb ^ 1;
            const size_t off = (size_t)((tc + 1 < ct) ? tc + 1 : tc) * 65536;
            f32x4 gnx[4];
            #pragma unroll
            for (int ti = 0; ti < 4; ++ti)
                gnx[ti] = *(const f32x4*)(gx + off + (size_t)((wv + 8 * ti) * 16 + cc) * 16 + 4 * q);

            // A frags: conflict-free sequential b128 reads
            bf16x8 ahi[4], alo[4];
            #pragma unroll
            for (int ks = 0; ks < 4; ++ks) {
                ahi[ks] = *(const bf16x8*)&hfhi[rb][ks * 4 + q][cc][0];
                alo[ks] = *(const bf16x8*)&hflo[rb][ks * 4 + q][cc][0];
            }

            f32x4 acc[4];
            #pragma unroll
            for (int ti = 0; ti < 4; ++ti) {
                f32x4 dd = gcur[ti];
                #pragma unroll
                for (int ks = 0; ks < 4; ++ks)
                    dd = __builtin_amdgcn_mfma_f32_16x16x32_bf16(ahi[ks], bh[ti][ks], dd, 0, 0, 0);
                #pragma unroll
                for (int ks = 0; ks < 4; ++ks)
                    dd = __builtin_amdgcn_mfma_f32_16x16x32_bf16(ahi[ks], bl[ti][ks], dd, 0, 0, 0);
                #pragma unroll
                for (int ks = 0; ks < 4; ++ks)
                    dd = __builtin_amdgcn_mfma_f32_16x16x32_bf16(alo[ks], bh[ti][ks], dd, 0, 0, 0);
                acc[ti] = dd;
            }
            #pragma unroll
            for (int ti = 0; ti < 4; ++ti) gcur[ti] = gnx[ti];

            // activations: lane owns samples 4q+r, unit uu (all 64 lanes active)
            #pragma unroll
            for (int r = 0; r < 4; ++r) {
                float gi = sigmoidf_fast(acc[0][r]);
                float gf = sigmoidf_fast(acc[1][r]);
                float gg = tanhf_fast(acc[2][r]);
                float go = sigmoidf_fast(acc[3][r]);
                float cn = gf * cstate[r] + gi * gg;
                cstate[r] = cn;
                hv[r] = go * tanhf_fast(cn);
                __bf16 hb = (__bf16)hv[r];
                __bf16 lb = (__bf16)(hv[r] - (float)hb);
                int s = 4 * q + r;
                hfhi[wb][uu >> 3][s][uu & 7] = hb;
                hflo[wb][uu >> 3][s][uu & 7] = lb;
                if (lr < 2) {
                    size_t zi = ((size_t)tc * N_BATCH + sbase + s) * HD + uu;
                    zho[zi] = hb; zlo_[zi] = lb;
                }
            }
            __syncthreads();
        }
        #pragma unroll
        for (int r = 0; r < 4; ++r) {
            cst[(size_t)(sbase + 4 * q + r) * HD + uu] = cstate[r];
            hprev[(size_t)(sbase + 4 * q + r) * HD + uu] = hv[r];
        }
    } else {
        // ---------------- gemm role (produces gx for dispatch d+1) ----------------
        const int g = bx - 24;
        const int perl = 2 * ct;
        const int lg = g / perl;
        const int r0 = g - lg * perl;
        const int cg = d + 1 - 2 * lg;
        if (cg < 0 || cg >= nchunk) return;
        const int tg4 = r0 >> 3;             // timestep group (4 steps)
        const int gb = (r0 >> 1) & 3;        // gate block (128 gates)
        const int nb = r0 & 1;               // sample half (64)

        const __bf16* zh = nullptr; const __bf16* zl = nullptr;
        if (lg > 0) {
            size_t po = (size_t)((d & 1) ^ 1) * zchunk;
            zh = ((lg == 1) ? z1hi : z2hi) + po;
            zl = ((lg == 1) ? z1lo : z2lo) + po;
        }

        const int mt0 = gb * 8 + (wv & 3) * 2;   // 2 M-tiles (gates)
        const int nt0 = (wv >> 2) * 2;           // 2 N-tiles (samples)

        // A frags: Wih rows (reused over 4 timesteps)
        bf16x8 ah[2][4], al[2][4];
        #pragma unroll
        for (int mm = 0; mm < 2; ++mm) {
            int row = (mt0 + mm) * 16 + cc;
            #pragma unroll
            for (int ks = 0; ks < 4; ++ks) {
                ah[mm][ks] = *(const bf16x8*)(wih_hi + (size_t)lg * 65536 + (size_t)row * HD + ks * 32 + q * 8);
                al[mm][ks] = *(const bf16x8*)(wih_lo + (size_t)lg * 65536 + (size_t)row * HD + ks * 32 + q * 8);
            }
        }

        float* __restrict__ gxo0 = gxbase + (size_t)(((d + 1) & 1) * 3 + lg) * gxl;

        for (int t4 = 0; t4 < 4; ++t4) {
            const int tc = tg4 * 4 + t4;
            // B frags: z (or split x/w) cols n
            bf16x8 zbh[2][4], zbl[2][4];
            #pragma unroll
            for (int nn = 0; nn < 2; ++nn) {
                int n = nb * 64 + (nt0 + nn) * 16 + cc;
                if (lg == 0) {
                    int tg = cg * ct + tc;
                    #pragma unroll
                    for (int ks = 0; ks < 4; ++ks) {
                        const float* src = (ks < 2 ? x : w)
                            + ((size_t)n * L_SEQ + tg) * 64 + (ks & 1) * 32 + q * 8;
                        split8(src, zbh[nn][ks], zbl[nn][ks]);
                    }
                } else {
                    size_t row = (size_t)tc * N_BATCH + n;
                    #pragma unroll
                    for (int ks = 0; ks < 4; ++ks) {
                        zbh[nn][ks] = *(const bf16x8*)(zh + row * HD + ks * 32 + q * 8);
                        zbl[nn][ks] = *(const bf16x8*)(zl + row * HD + ks * 32 + q * 8);
                    }
                }
            }

            f32x4 acc[2][2];
            #pragma unroll
            for (int mm = 0; mm < 2; ++mm)
                #pragma unroll
                for (int nn = 0; nn < 2; ++nn) {
                    f32x4 dd; dd[0] = dd[1] = dd[2] = dd[3] = 0.f;
                    #pragma unroll
                    for (int ks = 0; ks < 4; ++ks)
                        dd = __builtin_amdgcn_mfma_f32_16x16x32_bf16(ah[mm][ks], zbh[nn][ks], dd, 0, 0, 0);
                    #pragma unroll
                    for (int ks = 0; ks < 4; ++ks)
                        dd = __builtin_amdgcn_mfma_f32_16x16x32_bf16(ah[mm][ks], zbl[nn][ks], dd, 0, 0, 0);
                    #pragma unroll
                    for (int ks = 0; ks < 4; ++ks)
                        dd = __builtin_amdgcn_mfma_f32_16x16x32_bf16(al[mm][ks], zbh[nn][ks], dd, 0, 0, 0);
                    acc[mm][nn] = dd;
                }

            float* __restrict__ gxo = gxo0 + (size_t)tc * 65536;
            #pragma unroll
            for (int mm = 0; mm < 2; ++mm) {
                f32x4 bb = *(const f32x4*)(bsum + (size_t)lg * G4 + (mt0 + mm) * 16 + 4 * q);
                #pragma unroll
                for (int nn = 0; nn < 2; ++nn) {
                    int sb = nb * 4 + nt0 + nn;
                    #pragma unroll
                    for (int rr = 0; rr < 4; ++rr) {
                        int grow = (mt0 + mm) * 16 + 4 * q + rr;
                        gxo[(size_t)sb * 8192 + (size_t)grow * 16 + cc] = acc[mm][nn][rr] + bb[rr];
                    }
                }
            }
        }
    }
}

__global__ void final_lin(const float* __restrict__ hlast,
                          const float* __restrict__ Wlin,
                          const float* __restrict__ blin,
                          float* __restrict__ out)
{
    int n = threadIdx.x;  // 128
    const float4* h4 = (const float4*)(hlast + (size_t)n * HD);
    const float4* w4 = (const float4*)Wlin;
    float s = 0.f;
    #pragma unroll
    for (int k4 = 0; k4 < 32; ++k4) {
        float4 h = h4[k4];
        float4 ww = w4[k4];
        s += h.x * ww.x + h.y * ww.y + h.z * ww.z + h.w * ww.w;
    }
    out[n] = s + blin[0];
}

extern "C" void kernel_launch(void* const* d_in, const int* in_sizes, int n_in,
                              void* d_out, int out_size, void* d_ws, size_t ws_size,
                              hipStream_t stream)
{
    const float* x = (const float*)d_in[0];
    const float* w = (const float*)d_in[1];
    const float* Wih[3] = {(const float*)d_in[2], (const float*)d_in[6], (const float*)d_in[10]};
    const float* Whh[3] = {(const float*)d_in[3], (const float*)d_in[7], (const float*)d_in[11]};
    const float* bih[3] = {(const float*)d_in[4], (const float*)d_in[8], (const float*)d_in[12]};
    const float* bhh[3] = {(const float*)d_in[5], (const float*)d_in[9], (const float*)d_in[13]};
    const float* Wlin = (const float*)d_in[14];
    const float* blin = (const float*)d_in[15];
    float* out = (float*)d_out;

    // bytes = 1,835,008*ct + ~2MB fixed
    int ct = 8;
    const int cands[4] = {64, 32, 16, 8};
    for (int i = 0; i < 4; ++i) {
        size_t need = 1835008ull * cands[i] + 2100000ull;
        if (need <= ws_size) { ct = cands[i]; break; }
    }
    const int nchunk = L_SEQ / ct;

    float* gxbase = (float*)d_ws;                       // 6*ct*65536 floats
    float* carry  = gxbase + (size_t)6 * ct * 65536;    // 98304 floats
    float* bsum   = carry + 98304;                      // 1536 floats
    __bf16* whh_hi = (__bf16*)(bsum + 1536);
    __bf16* whh_lo = whh_hi + 196608;
    __bf16* wih_hi = whh_lo + 196608;
    __bf16* wih_lo = wih_hi + 196608;
    __bf16* z1hi = wih_lo + 196608;                     // each 2*ct*16384 bf16
    __bf16* z1lo = z1hi + (size_t)2 * ct * 16384;
    __bf16* z2hi = z1lo + (size_t)2 * ct * 16384;
    __bf16* z2lo = z2hi + (size_t)2 * ct * 16384;

    prep_split<<<dim3(1536), dim3(256), 0, stream>>>(
        Whh[0], Whh[1], Whh[2], Wih[0], Wih[1], Wih[2],
        bih[0], bih[1], bih[2], bhh[0], bhh[1], bhh[2],
        whh_hi, whh_lo, wih_hi, wih_lo, bsum);

    const int nblk = 24 + 6 * ct;
    for (int d = -1; d <= nchunk + 3; ++d) {
        stage_kernel<<<dim3(nblk), dim3(512), 0, stream>>>(
            x, w, whh_hi, whh_lo, wih_hi, wih_lo, bsum,
            gxbase, z1hi, z1lo, z2hi, z2lo, carry, d, ct, nchunk);
    }
    final_lin<<<dim3(1), dim3(128), 0, stream>>>(carry + 2 * 16384, Wlin, blin, out);
}